// Round 6
// baseline (127.767 us; speedup 1.0000x reference)
//
#include <hip/hip_runtime.h>
#include <hip/hip_bf16.h>

#define NN 256
#define CIN 96
#define COUT 96
#define BB 4
#define NBC (BB * CIN)          /* 384 */
#define SEG (NBC * NN)          /* 98304 */

typedef __attribute__((ext_vector_type(8))) short short8;
typedef __attribute__((ext_vector_type(4))) float f32x4;

__device__ __forceinline__ float waveReduceSum(float v) {
    #pragma unroll
    for (int m = 32; m >= 1; m >>= 1) v += __shfl_xor(v, m, 64);
    return v;
}

__device__ __forceinline__ unsigned int packbf2(float lo, float hi) {
    __hip_bfloat162 h = __float22bfloat162_rn(make_float2(lo, hi));
    unsigned int u;
    __builtin_memcpy(&u, &h, 4);
    return u;
}

__device__ __forceinline__ short8 u4_to_s8(uint4 u) {
    short8 r;
    __builtin_memcpy(&r, &u, 16);
    return r;
}

// ---------------- K1: per (b,c) chunked rowsum / colsum-partial / diag / T,S-partial ----
// 1536 blocks (bc*4+ch); block handles 64 rows of one (b,c). 8 loads in flight/wave.
__global__ __launch_bounds__(256) void k_aux(const float* __restrict__ X,
                                             float* __restrict__ rows,
                                             float* __restrict__ diag,
                                             float* __restrict__ colsP,
                                             float* __restrict__ TSp) {
    const int blk = blockIdx.x;
    const int ch = blk & 3, bc = blk >> 2;
    const float* Xp = X + (size_t)bc * (NN * NN) + (size_t)ch * 64 * NN;
    const int tid = threadIdx.x;
    const int w = tid >> 6, lane = tid & 63;

    __shared__ float colPart[4][NN];
    __shared__ float sred[4];

    float4 csum = make_float4(0.f, 0.f, 0.f, 0.f);
    #pragma unroll
    for (int b2 = 0; b2 < 2; ++b2) {
        float4 v[8];
        #pragma unroll
        for (int j = 0; j < 8; ++j) {
            const int r = w * 16 + b2 * 8 + j;
            v[j] = *(const float4*)(Xp + (size_t)r * NN + lane * 4);
        }
        #pragma unroll
        for (int j = 0; j < 8; ++j) {
            csum.x += v[j].x; csum.y += v[j].y; csum.z += v[j].z; csum.w += v[j].w;
            float rs = waveReduceSum(v[j].x + v[j].y + v[j].z + v[j].w);
            if (lane == 0)
                rows[(size_t)bc * NN + ch * 64 + w * 16 + b2 * 8 + j] = rs;
        }
    }
    *(float4*)&colPart[w][lane * 4] = csum;

    // diag chunk + T partial (wave 0)
    if (w == 0) {
        float dv = Xp[(size_t)lane * NN + ch * 64 + lane];
        diag[(size_t)bc * NN + ch * 64 + lane] = dv;
        float t1 = waveReduceSum(dv);
        if (lane == 0) TSp[(ch * NBC + bc) * 2 + 0] = t1;
    }
    __syncthreads();

    float col = colPart[0][tid] + colPart[1][tid] + colPart[2][tid] + colPart[3][tid];
    colsP[(size_t)ch * SEG + (size_t)bc * NN + tid] = col;
    float s1 = waveReduceSum(col);
    if (lane == 0) sred[w] = s1;
    __syncthreads();
    if (tid == 0)
        TSp[(ch * NBC + bc) * 2 + 1] = sred[0] + sred[1] + sred[2] + sred[3];
}

// ---------------- K2: P' / Q / G' per (b,o,p), c-split x4 ----------------
__global__ __launch_bounds__(1024) void k_pqg(const float* __restrict__ W,
                                              const float* __restrict__ rows,
                                              const float* __restrict__ diag,
                                              const float* __restrict__ colsP,
                                              const float* __restrict__ TSp,
                                              const float* __restrict__ bias,
                                              float* __restrict__ Pw,
                                              float* __restrict__ Qw,
                                              float* __restrict__ Gw) {
    const int bo = blockIdx.x;
    const int b = bo / COUT, o = bo % COUT;
    const int qtr = threadIdx.x >> 8;
    const int p = threadIdx.x & 255;

    __shared__ float red[3][5][256];

    float P = 0.f, Q = 0.f, G = 0.f, s = 0.f, gs = 0.f;
    const int cbeg = qtr * 24, cend = cbeg + 24;
    for (int c = cbeg; c < cend; ++c) {
        const int bcq = b * CIN + c;
        const size_t base = (size_t)bcq * NN;
        float r  = rows[base + p];
        float cl = colsP[0 * SEG + base + p] + colsP[1 * SEG + base + p]
                 + colsP[2 * SEG + base + p] + colsP[3 * SEG + base + p];
        float dg = diag[base + p];
        const float* wp = W + c * COUT + o;
        #define WI(i) wp[(i) * CIN * COUT]
        P += WI(12) * r + WI(7)  * cl + WI(5) * dg;
        Q += WI(13) * r + WI(10) * cl + WI(9) * dg;
        G += WI(3)  * r + WI(1)  * cl + WI(0) * dg;
        float Tv = TSp[(0 * NBC + bcq) * 2] + TSp[(1 * NBC + bcq) * 2]
                 + TSp[(2 * NBC + bcq) * 2] + TSp[(3 * NBC + bcq) * 2];
        float Sv = TSp[(0 * NBC + bcq) * 2 + 1] + TSp[(1 * NBC + bcq) * 2 + 1]
                 + TSp[(2 * NBC + bcq) * 2 + 1] + TSp[(3 * NBC + bcq) * 2 + 1];
        s  += WI(11) * Tv + WI(14) * Sv;
        gs += WI(2)  * Tv + WI(4)  * Sv;
        #undef WI
    }
    if (qtr) {
        red[qtr - 1][0][p] = P; red[qtr - 1][1][p] = Q; red[qtr - 1][2][p] = G;
        red[qtr - 1][3][p] = s; red[qtr - 1][4][p] = gs;
    }
    __syncthreads();
    if (qtr == 0) {
        P += red[0][0][p] + red[1][0][p] + red[2][0][p];
        Q += red[0][1][p] + red[1][1][p] + red[2][1][p];
        G += red[0][2][p] + red[1][2][p] + red[2][2][p];
        s += red[0][3][p] + red[1][3][p] + red[2][3][p];
        gs += red[0][4][p] + red[1][4][p] + red[2][4][p];
        const size_t ob = (size_t)bo * NN;
        Pw[ob + p] = P + s + bias[0];
        Qw[ob + p] = Q;
        Gw[ob + p] = G + gs;
    }
}

// ---------------- K3: MFMA channel-mix, conflict-free LDS ----------------
#define XPLANE 324
#define WPLANE 100

__global__ __launch_bounds__(512, 1) void k_main(const float* __restrict__ X,
                                                 const float* __restrict__ W,
                                                 const float* __restrict__ Pw,
                                                 const float* __restrict__ Qw,
                                                 const float* __restrict__ Gw,
                                                 float* __restrict__ Y) {
    __shared__ __align__(16) unsigned int XAs[16 * XPLANE];
    __shared__ __align__(16) unsigned int XBs[16 * XPLANE];
    __shared__ __align__(16) unsigned int W8s[16 * WPLANE];
    __shared__ __align__(16) unsigned int W6s[16 * WPLANE];

    const int orig = blockIdx.x + 16 * (blockIdx.y + 16 * blockIdx.z);
    const int work = (orig & 7) * 128 + (orig >> 3);
    const int tq = work & 15, tp = (work >> 4) & 15, b = work >> 8;

    const int tid = threadIdx.x;
    const int w = tid >> 6, lane = tid & 63;
    const int sp = lane >> 2, sq4 = (lane & 3) * 4;
    const int col = lane & 15, g = lane >> 4;

    f32x4 acc[6][2];
    #pragma unroll
    for (int m = 0; m < 6; ++m) {
        acc[m][0] = f32x4{0.f, 0.f, 0.f, 0.f};
        acc[m][1] = f32x4{0.f, 0.f, 0.f, 0.f};
    }

    const float* Xb  = X + (size_t)b * CIN * NN * NN;
    const float* G1  = Xb + (size_t)(tp * 16) * NN + tq * 16;
    const float* G2  = Xb + (size_t)(tq * 16) * NN + tp * 16;
    const float* w8g = W + 8 * CIN * COUT;
    const float* w6g = W + 6 * CIN * COUT;

    for (int c0 = 0; c0 < CIN; c0 += 32) {
        __syncthreads();

        #pragma unroll
        for (int h = 0; h < 2; ++h) {
            const int cw = w + 8 * h;
            const size_t cb = (size_t)(c0 + 2 * cw) * (NN * NN);
            const float* pa = G1 + cb + sp * NN + sq4;
            float4 a0 = *(const float4*)pa;
            float4 a1 = *(const float4*)(pa + NN * NN);
            uint4 pk;
            pk.x = packbf2(a0.x, a1.x);
            pk.y = packbf2(a0.y, a1.y);
            pk.z = packbf2(a0.z, a1.z);
            pk.w = packbf2(a0.w, a1.w);
            *(uint4*)&XAs[cw * XPLANE + sp * 20 + sq4] = pk;

            const float* pb = G2 + cb + sp * NN + sq4;
            float4 b0 = *(const float4*)pb;
            float4 b1 = *(const float4*)(pb + NN * NN);
            unsigned int* dB = &XBs[cw * XPLANE + sp];
            dB[(sq4 + 0) * 20] = packbf2(b0.x, b1.x);
            dB[(sq4 + 1) * 20] = packbf2(b0.y, b1.y);
            dB[(sq4 + 2) * 20] = packbf2(b0.z, b1.z);
            dB[(sq4 + 3) * 20] = packbf2(b0.w, b1.w);
        }
        #pragma unroll
        for (int it = 0; it < 3; ++it) {
            const int i  = tid + it * 512;
            const int cw = i / 96, o = i - cw * 96;
            const int cg = (c0 + 2 * cw) * COUT + o;
            W8s[cw * WPLANE + o] = packbf2(w8g[cg], w8g[cg + COUT]);
            W6s[cw * WPLANE + o] = packbf2(w6g[cg], w6g[cg + COUT]);
        }
        __syncthreads();

        const unsigned int* xab = &XAs[4 * g * XPLANE + w * 20 + col];
        const unsigned int* xbb = &XBs[4 * g * XPLANE + w * 20 + col];
        uint4 u;
        u.x = xab[0]; u.y = xab[XPLANE]; u.z = xab[2 * XPLANE]; u.w = xab[3 * XPLANE];
        short8 xd0 = u4_to_s8(u);
        u.x = xab[160]; u.y = xab[XPLANE + 160]; u.z = xab[2 * XPLANE + 160]; u.w = xab[3 * XPLANE + 160];
        short8 xd1 = u4_to_s8(u);
        u.x = xbb[0]; u.y = xbb[XPLANE]; u.z = xbb[2 * XPLANE]; u.w = xbb[3 * XPLANE];
        short8 xt0 = u4_to_s8(u);
        u.x = xbb[160]; u.y = xbb[XPLANE + 160]; u.z = xbb[2 * XPLANE + 160]; u.w = xbb[3 * XPLANE + 160];
        short8 xt1 = u4_to_s8(u);

        #pragma unroll
        for (int m = 0; m < 6; ++m) {
            const unsigned int* wp8 = &W8s[4 * g * WPLANE + m * 16 + col];
            const unsigned int* wp6 = &W6s[4 * g * WPLANE + m * 16 + col];
            uint4 v8, v6;
            v8.x = wp8[0]; v8.y = wp8[WPLANE]; v8.z = wp8[2 * WPLANE]; v8.w = wp8[3 * WPLANE];
            v6.x = wp6[0]; v6.y = wp6[WPLANE]; v6.z = wp6[2 * WPLANE]; v6.w = wp6[3 * WPLANE];
            short8 w8f = u4_to_s8(v8);
            short8 w6f = u4_to_s8(v6);
            acc[m][0] = __builtin_amdgcn_mfma_f32_16x16x32_bf16(xd0, w8f, acc[m][0], 0, 0, 0);
            acc[m][0] = __builtin_amdgcn_mfma_f32_16x16x32_bf16(xt0, w6f, acc[m][0], 0, 0, 0);
            acc[m][1] = __builtin_amdgcn_mfma_f32_16x16x32_bf16(xd1, w8f, acc[m][1], 0, 0, 0);
            acc[m][1] = __builtin_amdgcn_mfma_f32_16x16x32_bf16(xt1, w6f, acc[m][1], 0, 0, 0);
        }
    }

    const int p0 = tp * 16 + w;
    const int q4 = tq * 16 + g * 4;
    const bool diagblk = (tp == tq);
    #pragma unroll
    for (int m = 0; m < 6; ++m) {
        const int o = m * 16 + col;
        const size_t ob = (size_t)(b * COUT + o) * NN;
        const float4 qf = *(const float4*)&Qw[ob + q4];
        #pragma unroll
        for (int rr = 0; rr < 2; ++rr) {
            const int p = p0 + rr * 8;
            const float pv = Pw[ob + p];
            float4 out;
            out.x = acc[m][rr][0] + pv + qf.x;
            out.y = acc[m][rr][1] + pv + qf.y;
            out.z = acc[m][rr][2] + pv + qf.z;
            out.w = acc[m][rr][3] + pv + qf.w;
            if (diagblk) {
                const float gv = Gw[ob + p];
                const int d = (p & 15) - g * 4;
                if (d == 0) out.x += gv;
                else if (d == 1) out.y += gv;
                else if (d == 2) out.z += gv;
                else if (d == 3) out.w += gv;
            }
            *(float4*)&Y[(ob + p) * NN + q4] = out;
        }
    }
}

extern "C" void kernel_launch(void* const* d_in, const int* in_sizes, int n_in,
                              void* d_out, int out_size, void* d_ws, size_t ws_size,
                              hipStream_t stream) {
    const float* X    = (const float*)d_in[0];
    const float* W    = (const float*)d_in[2];   // [15][96][96]
    const float* bias = (const float*)d_in[3];
    float* Y = (float*)d_out;

    float* ws    = (float*)d_ws;
    float* rows  = ws;
    float* diag  = ws + SEG;
    float* colsP = ws + 2 * (size_t)SEG;          // 4 chunks -> 4*SEG
    float* Pw    = ws + 6 * (size_t)SEG;
    float* Qw    = ws + 7 * (size_t)SEG;
    float* Gw    = ws + 8 * (size_t)SEG;
    float* TSp   = ws + 9 * (size_t)SEG;          // 4*NBC*2 floats

    k_aux<<<NBC * 4, 256, 0, stream>>>(X, rows, diag, colsP, TSp);
    k_pqg<<<BB * COUT, 1024, 0, stream>>>(W, rows, diag, colsP, TSp, bias, Pw, Qw, Gw);
    k_main<<<dim3(16, 16, BB), 512, 0, stream>>>(X, W, Pw, Qw, Gw, Y);
}

// Round 7
// 111.369 us; speedup vs baseline: 1.1472x; 1.1472x over previous
//
#include <hip/hip_runtime.h>
#include <hip/hip_bf16.h>

#define NN 256
#define CIN 96
#define COUT 96
#define BB 4
#define NBC (BB * CIN)          /* 384 */
#define SEG (NBC * NN)          /* 98304 */

typedef __attribute__((ext_vector_type(8))) short short8;
typedef __attribute__((ext_vector_type(4))) float f32x4;

__device__ __forceinline__ float waveReduceSum(float v) {
    #pragma unroll
    for (int m = 32; m >= 1; m >>= 1) v += __shfl_xor(v, m, 64);
    return v;
}

__device__ __forceinline__ unsigned int packbf2(float lo, float hi) {
    __hip_bfloat162 h = __float22bfloat162_rn(make_float2(lo, hi));
    unsigned int u;
    __builtin_memcpy(&u, &h, 4);
    return u;
}

__device__ __forceinline__ short8 u4_to_s8(uint4 u) {
    short8 r;
    __builtin_memcpy(&r, &u, 16);
    return r;
}

// ---------------- K1: per (b,c) chunked rowsum / colsum-partial / diag / T,S-partial ----
__global__ __launch_bounds__(256) void k_aux(const float* __restrict__ X,
                                             float* __restrict__ rows,
                                             float* __restrict__ diag,
                                             float* __restrict__ colsP,
                                             float* __restrict__ TSp) {
    const int blk = blockIdx.x;
    const int ch = blk & 3, bc = blk >> 2;
    const float* Xp = X + (size_t)bc * (NN * NN) + (size_t)ch * 64 * NN;
    const int tid = threadIdx.x;
    const int w = tid >> 6, lane = tid & 63;

    __shared__ float colPart[4][NN];
    __shared__ float sred[4];

    float4 csum = make_float4(0.f, 0.f, 0.f, 0.f);
    #pragma unroll
    for (int b2 = 0; b2 < 2; ++b2) {
        float4 v[8];
        #pragma unroll
        for (int j = 0; j < 8; ++j) {
            const int r = w * 16 + b2 * 8 + j;
            v[j] = *(const float4*)(Xp + (size_t)r * NN + lane * 4);
        }
        #pragma unroll
        for (int j = 0; j < 8; ++j) {
            csum.x += v[j].x; csum.y += v[j].y; csum.z += v[j].z; csum.w += v[j].w;
            float rs = waveReduceSum(v[j].x + v[j].y + v[j].z + v[j].w);
            if (lane == 0)
                rows[(size_t)bc * NN + ch * 64 + w * 16 + b2 * 8 + j] = rs;
        }
    }
    *(float4*)&colPart[w][lane * 4] = csum;

    if (w == 0) {
        float dv = Xp[(size_t)lane * NN + ch * 64 + lane];
        diag[(size_t)bc * NN + ch * 64 + lane] = dv;
        float t1 = waveReduceSum(dv);
        if (lane == 0) TSp[(ch * NBC + bc) * 2 + 0] = t1;
    }
    __syncthreads();

    float col = colPart[0][tid] + colPart[1][tid] + colPart[2][tid] + colPart[3][tid];
    colsP[(size_t)ch * SEG + (size_t)bc * NN + tid] = col;
    float s1 = waveReduceSum(col);
    if (lane == 0) sred[w] = s1;
    __syncthreads();
    if (tid == 0)
        TSp[(ch * NBC + bc) * 2 + 1] = sred[0] + sred[1] + sred[2] + sred[3];
}

// ---------------- K1b: fold partials ----------------
__global__ __launch_bounds__(256) void k_sum(const float* __restrict__ colsP,
                                             const float* __restrict__ TSp,
                                             float* __restrict__ cols,
                                             float* __restrict__ TSa) {
    const int bc = blockIdx.x;
    const int p = threadIdx.x;
    const size_t base = (size_t)bc * NN + p;
    cols[base] = colsP[0 * (size_t)SEG + base] + colsP[1 * (size_t)SEG + base]
               + colsP[2 * (size_t)SEG + base] + colsP[3 * (size_t)SEG + base];
    if (p < 2)
        TSa[bc * 2 + p] = TSp[(0 * NBC + bc) * 2 + p] + TSp[(1 * NBC + bc) * 2 + p]
                        + TSp[(2 * NBC + bc) * 2 + p] + TSp[(3 * NBC + bc) * 2 + p];
}

// ---------------- K2: P' / Q / G' per (b,o,p), c-split x2 (proven round-5 form) ----
__global__ __launch_bounds__(512) void k_pqg(const float* __restrict__ W,
                                             const float* __restrict__ rows,
                                             const float* __restrict__ cols,
                                             const float* __restrict__ diag,
                                             const float* __restrict__ TSa,
                                             const float* __restrict__ bias,
                                             float* __restrict__ Pw,
                                             float* __restrict__ Qw,
                                             float* __restrict__ Gw) {
    const int bo = blockIdx.x;
    const int b = bo / COUT, o = bo % COUT;
    const int half = threadIdx.x >> 8;
    const int p = threadIdx.x & 255;

    __shared__ float red[5][256];

    float P = 0.f, Q = 0.f, G = 0.f, s = 0.f, gs = 0.f;
    const int cbeg = half * 48, cend = cbeg + 48;
    for (int c = cbeg; c < cend; ++c) {
        const int bcq = b * CIN + c;
        const size_t base = (size_t)bcq * NN;
        float r  = rows[base + p];
        float cl = cols[base + p];
        float dg = diag[base + p];
        const float* wp = W + c * COUT + o;
        #define WI(i) wp[(i) * CIN * COUT]
        P += WI(12) * r + WI(7)  * cl + WI(5) * dg;
        Q += WI(13) * r + WI(10) * cl + WI(9) * dg;
        G += WI(3)  * r + WI(1)  * cl + WI(0) * dg;
        float Tv = TSa[bcq * 2 + 0];
        float Sv = TSa[bcq * 2 + 1];
        s  += WI(11) * Tv + WI(14) * Sv;
        gs += WI(2)  * Tv + WI(4)  * Sv;
        #undef WI
    }
    if (half == 1) {
        red[0][p] = P; red[1][p] = Q; red[2][p] = G; red[3][p] = s; red[4][p] = gs;
    }
    __syncthreads();
    if (half == 0) {
        P += red[0][p]; Q += red[1][p]; G += red[2][p]; s += red[3][p]; gs += red[4][p];
        const size_t ob = (size_t)bo * NN;
        Pw[ob + p] = P + s + bias[0];
        Qw[ob + p] = Q;
        Gw[ob + p] = G + gs;
    }
}

// ---------------- K3: MFMA channel-mix, conflict-free LDS + async-stage prefetch ----
#define XPLANE 324
#define WPLANE 100

__global__ __launch_bounds__(512, 1) void k_main(const float* __restrict__ X,
                                                 const float* __restrict__ W,
                                                 const float* __restrict__ Pw,
                                                 const float* __restrict__ Qw,
                                                 const float* __restrict__ Gw,
                                                 float* __restrict__ Y) {
    __shared__ __align__(16) unsigned int XAs[16 * XPLANE];
    __shared__ __align__(16) unsigned int XBs[16 * XPLANE];
    __shared__ __align__(16) unsigned int W8s[16 * WPLANE];
    __shared__ __align__(16) unsigned int W6s[16 * WPLANE];

    const int orig = blockIdx.x + 16 * (blockIdx.y + 16 * blockIdx.z);
    const int work = (orig & 7) * 128 + (orig >> 3);
    const int tq = work & 15, tp = (work >> 4) & 15, b = work >> 8;

    const int tid = threadIdx.x;
    const int w = tid >> 6, lane = tid & 63;
    const int sp = lane >> 2, sq4 = (lane & 3) * 4;
    const int col = lane & 15, g = lane >> 4;

    f32x4 acc[6][2];
    #pragma unroll
    for (int m = 0; m < 6; ++m) {
        acc[m][0] = f32x4{0.f, 0.f, 0.f, 0.f};
        acc[m][1] = f32x4{0.f, 0.f, 0.f, 0.f};
    }

    const float* Xb  = X + (size_t)b * CIN * NN * NN;
    const float* G1  = Xb + (size_t)(tp * 16) * NN + tq * 16;
    const float* G2  = Xb + (size_t)(tq * 16) * NN + tp * 16;
    const float* w8g = W + 8 * CIN * COUT;
    const float* w6g = W + 6 * CIN * COUT;

    const int cw0 = w, cw1 = w + 8;

    // in-flight staging registers (named, never runtime-indexed)
    float4 a00, a01, b00, b01;     // channel pair cw0
    float4 a10, a11, b10, b11;     // channel pair cw1

    #define LOADG(C0) { \
        const size_t cb0 = (size_t)((C0) + 2 * cw0) * (NN * NN); \
        const size_t cb1 = (size_t)((C0) + 2 * cw1) * (NN * NN); \
        const float* pa0 = G1 + cb0 + sp * NN + sq4; \
        a00 = *(const float4*)pa0; \
        a01 = *(const float4*)(pa0 + NN * NN); \
        const float* pb0 = G2 + cb0 + sp * NN + sq4; \
        b00 = *(const float4*)pb0; \
        b01 = *(const float4*)(pb0 + NN * NN); \
        const float* pa1 = G1 + cb1 + sp * NN + sq4; \
        a10 = *(const float4*)pa1; \
        a11 = *(const float4*)(pa1 + NN * NN); \
        const float* pb1 = G2 + cb1 + sp * NN + sq4; \
        b10 = *(const float4*)pb1; \
        b11 = *(const float4*)(pb1 + NN * NN); }

    LOADG(0);

    for (int c0 = 0; c0 < CIN; c0 += 32) {
        __syncthreads();   // prev iter's LDS reads complete

        // ---- pack + store prefetched X ----
        {
            uint4 pk;
            pk.x = packbf2(a00.x, a01.x);
            pk.y = packbf2(a00.y, a01.y);
            pk.z = packbf2(a00.z, a01.z);
            pk.w = packbf2(a00.w, a01.w);
            *(uint4*)&XAs[cw0 * XPLANE + sp * 20 + sq4] = pk;
            pk.x = packbf2(a10.x, a11.x);
            pk.y = packbf2(a10.y, a11.y);
            pk.z = packbf2(a10.z, a11.z);
            pk.w = packbf2(a10.w, a11.w);
            *(uint4*)&XAs[cw1 * XPLANE + sp * 20 + sq4] = pk;
            unsigned int* dB0 = &XBs[cw0 * XPLANE + sp];
            dB0[(sq4 + 0) * 20] = packbf2(b00.x, b01.x);
            dB0[(sq4 + 1) * 20] = packbf2(b00.y, b01.y);
            dB0[(sq4 + 2) * 20] = packbf2(b00.z, b01.z);
            dB0[(sq4 + 3) * 20] = packbf2(b00.w, b01.w);
            unsigned int* dB1 = &XBs[cw1 * XPLANE + sp];
            dB1[(sq4 + 0) * 20] = packbf2(b10.x, b11.x);
            dB1[(sq4 + 1) * 20] = packbf2(b10.y, b11.y);
            dB1[(sq4 + 2) * 20] = packbf2(b10.z, b11.z);
            dB1[(sq4 + 3) * 20] = packbf2(b10.w, b11.w);
        }
        // ---- stage weights ----
        #pragma unroll
        for (int it = 0; it < 3; ++it) {
            const int i  = tid + it * 512;
            const int cw = i / 96, o = i - cw * 96;
            const int cg = (c0 + 2 * cw) * COUT + o;
            W8s[cw * WPLANE + o] = packbf2(w8g[cg], w8g[cg + COUT]);
            W6s[cw * WPLANE + o] = packbf2(w6g[cg], w6g[cg + COUT]);
        }
        __syncthreads();

        // ---- issue next tile's global loads (overlap with ds_read + MFMA) ----
        if (c0 + 32 < CIN) LOADG(c0 + 32);

        const unsigned int* xab = &XAs[4 * g * XPLANE + w * 20 + col];
        const unsigned int* xbb = &XBs[4 * g * XPLANE + w * 20 + col];
        uint4 u;
        u.x = xab[0]; u.y = xab[XPLANE]; u.z = xab[2 * XPLANE]; u.w = xab[3 * XPLANE];
        short8 xd0 = u4_to_s8(u);
        u.x = xab[160]; u.y = xab[XPLANE + 160]; u.z = xab[2 * XPLANE + 160]; u.w = xab[3 * XPLANE + 160];
        short8 xd1 = u4_to_s8(u);
        u.x = xbb[0]; u.y = xbb[XPLANE]; u.z = xbb[2 * XPLANE]; u.w = xbb[3 * XPLANE];
        short8 xt0 = u4_to_s8(u);
        u.x = xbb[160]; u.y = xbb[XPLANE + 160]; u.z = xbb[2 * XPLANE + 160]; u.w = xbb[3 * XPLANE + 160];
        short8 xt1 = u4_to_s8(u);

        #pragma unroll
        for (int m = 0; m < 6; ++m) {
            const unsigned int* wp8 = &W8s[4 * g * WPLANE + m * 16 + col];
            const unsigned int* wp6 = &W6s[4 * g * WPLANE + m * 16 + col];
            uint4 v8, v6;
            v8.x = wp8[0]; v8.y = wp8[WPLANE]; v8.z = wp8[2 * WPLANE]; v8.w = wp8[3 * WPLANE];
            v6.x = wp6[0]; v6.y = wp6[WPLANE]; v6.z = wp6[2 * WPLANE]; v6.w = wp6[3 * WPLANE];
            short8 w8f = u4_to_s8(v8);
            short8 w6f = u4_to_s8(v6);
            acc[m][0] = __builtin_amdgcn_mfma_f32_16x16x32_bf16(xd0, w8f, acc[m][0], 0, 0, 0);
            acc[m][0] = __builtin_amdgcn_mfma_f32_16x16x32_bf16(xt0, w6f, acc[m][0], 0, 0, 0);
            acc[m][1] = __builtin_amdgcn_mfma_f32_16x16x32_bf16(xd1, w8f, acc[m][1], 0, 0, 0);
            acc[m][1] = __builtin_amdgcn_mfma_f32_16x16x32_bf16(xt1, w6f, acc[m][1], 0, 0, 0);
        }
    }
    #undef LOADG

    const int p0 = tp * 16 + w;
    const int q4 = tq * 16 + g * 4;
    const bool diagblk = (tp == tq);
    #pragma unroll
    for (int m = 0; m < 6; ++m) {
        const int o = m * 16 + col;
        const size_t ob = (size_t)(b * COUT + o) * NN;
        const float4 qf = *(const float4*)&Qw[ob + q4];
        #pragma unroll
        for (int rr = 0; rr < 2; ++rr) {
            const int p = p0 + rr * 8;
            const float pv = Pw[ob + p];
            float4 out;
            out.x = acc[m][rr][0] + pv + qf.x;
            out.y = acc[m][rr][1] + pv + qf.y;
            out.z = acc[m][rr][2] + pv + qf.z;
            out.w = acc[m][rr][3] + pv + qf.w;
            if (diagblk) {
                const float gv = Gw[ob + p];
                const int d = (p & 15) - g * 4;
                if (d == 0) out.x += gv;
                else if (d == 1) out.y += gv;
                else if (d == 2) out.z += gv;
                else if (d == 3) out.w += gv;
            }
            *(float4*)&Y[(ob + p) * NN + q4] = out;
        }
    }
}

extern "C" void kernel_launch(void* const* d_in, const int* in_sizes, int n_in,
                              void* d_out, int out_size, void* d_ws, size_t ws_size,
                              hipStream_t stream) {
    const float* X    = (const float*)d_in[0];
    const float* W    = (const float*)d_in[2];   // [15][96][96]
    const float* bias = (const float*)d_in[3];
    float* Y = (float*)d_out;

    float* ws    = (float*)d_ws;
    float* rows  = ws;
    float* diag  = ws + (size_t)SEG;
    float* colsP = ws + 2 * (size_t)SEG;          // 4 chunks
    float* Pw    = ws + 6 * (size_t)SEG;
    float* Qw    = ws + 7 * (size_t)SEG;
    float* Gw    = ws + 8 * (size_t)SEG;
    float* TSp   = ws + 9 * (size_t)SEG;          // 4*NBC*2 floats
    float* TSa   = ws + 9 * (size_t)SEG + 4096;   // NBC*2 floats
    float* cols  = ws + 10 * (size_t)SEG;

    k_aux<<<NBC * 4, 256, 0, stream>>>(X, rows, diag, colsP, TSp);
    k_sum<<<NBC, 256, 0, stream>>>(colsP, TSp, cols, TSa);
    k_pqg<<<BB * COUT, 512, 0, stream>>>(W, rows, cols, diag, TSa, bias, Pw, Qw, Gw);
    k_main<<<dim3(16, 16, BB), 512, 0, stream>>>(X, W, Pw, Qw, Gw, Y);
}